// Round 6
// baseline (518.009 us; speedup 1.0000x reference)
//
#include <hip/hip_runtime.h>

// ---------------------------------------------------------------------------
// LoRA QKV fused projection on MI355X (gfx950)
// Weff-folding (LoRA into weights) + ONE bf16 MFMA GEMM (32x32x16 frags).
// R6: fix R5's 4-way LDS bank conflict on 32-row frag reads:
//   - 8-B-granule k-swizzle (key = (row>>1)&7) applied IN HBM by prep
//     (X and Weff stored pre-swizzled; staging DMA is fully linear)
//   - frag reads = 2x ds_read_b64 at XOR'd sub-chunk offsets (16 start-slots,
//     2 rows/slot per 32-row window = b64 structural floor -> 0 conflicts)
// Schedule (8-phase, counted vmcnt, setprio) unchanged from R4/R5.
// ---------------------------------------------------------------------------

#define GLOBAL_AS __attribute__((address_space(1)))
#define LDS_AS    __attribute__((address_space(3)))

typedef __attribute__((ext_vector_type(8)))  short short8;   // 8 bf16 (MFMA A/B frag)
typedef __attribute__((ext_vector_type(4)))  short short4v;  // 8 B (ds_read_b64)
typedef __attribute__((ext_vector_type(16))) float f32x16;   // 32x32 MFMA C/D frag

constexpr int Mdim = 8192;   // B*S
constexpr int Kdim = 4096;   // H
constexpr int NQ   = 4096;
constexpr int NKV  = 1024;
constexpr int NTOT = NQ + 2 * NKV;  // 6144
constexpr float LORA_SCALE = 2.0f;

constexpr int BM = 256, BN = 256;
constexpr int TILES_M = Mdim / BM;      // 32
constexpr int TILES_N = NTOT / BN;      // 24
constexpr int NWG = TILES_M * TILES_N;  // 768 (%8==0 -> bijective XCD swizzle)
constexpr int NSLICE = Kdim / 32;       // 128 K-slices of 32

constexpr int WEFF_BLOCKS = (NTOT / 64) * (Kdim / 512);  // 768
constexpr int CVT_BLOCKS  = 2048;
constexpr int AT_STRIDE   = 516;

__device__ __forceinline__ unsigned short f2bf(float f) {
    union { float f; unsigned int u; } a; a.f = f;
    unsigned int r = a.u + 0x7FFFu + ((a.u >> 16) & 1u);
    return (unsigned short)(r >> 16);
}

// ---------------------------------------------------------------------------
// Fused prep. Both outputs are stored k-PRESWIZZLED: within each 32-element
// (64-B) k-slice of row r, the 4-element (8-B) source group g lands at
// physical group g ^ ((r>>1)&7).
// ---------------------------------------------------------------------------
__global__ __launch_bounds__(256)
void prep_kernel(const float4* __restrict__ x4, unsigned short* __restrict__ Xbf,
                 const float* __restrict__ Wq, const float* __restrict__ Wk,
                 const float* __restrict__ Wv,
                 const float* __restrict__ Aq, const float* __restrict__ Bq,
                 const float* __restrict__ Ak, const float* __restrict__ Bk,
                 const float* __restrict__ Av, const float* __restrict__ Bv,
                 unsigned short* __restrict__ Wf) {
    __shared__ float AsT[16 * AT_STRIDE];   // ~33 KB: A^T chunk, [r][h_local]
    __shared__ float Bsc[64 * 16];          // 4 KB: 2*B[r, n0+..] as [n][r]

    const int tid = threadIdx.x;

    if (blockIdx.x >= WEFF_BLOCKS) {
        // ---- X fp32 -> bf16, k-preswizzled write (one float4 = one 8-B group) ----
        int i = (blockIdx.x - WEFF_BLOCKS) * 256 + tid;
        const int stride = CVT_BLOCKS * 256;
        const int n4 = Mdim * Kdim / 4;
        ushort4* out = (ushort4*)Xbf;
        for (; i < n4; i += stride) {
            float4 v = x4[i];
            ushort4 u;
            u.x = f2bf(v.x); u.y = f2bf(v.y); u.z = f2bf(v.z); u.w = f2bf(v.w);
            const int r = i >> 10;                       // row
            const int key = (r >> 1) & 7;
            out[(i & ~7) | ((i & 7) ^ key)] = u;
        }
        return;
    }

    const int n0 = (blockIdx.x >> 3) * 64;      // 64-row group (never straddles seg)
    const int h0 = (blockIdx.x & 7) * 512;

    const float* W; const float* A; const float* Bm; int O; int nn0;
    if (n0 < NQ)            { W = Wq; A = Aq; Bm = Bq; O = NQ;  nn0 = n0; }
    else if (n0 < NQ + NKV) { W = Wk; A = Ak; Bm = Bk; O = NKV; nn0 = n0 - NQ; }
    else                    { W = Wv; A = Av; Bm = Bv; O = NKV; nn0 = n0 - NQ - NKV; }

    {
        const float4* Af4 = (const float4*)(A) + h0 * 4;
        #pragma unroll
        for (int i = 0; i < 8; ++i) {
            const int f = i * 256 + tid;
            const float4 v = Af4[f];
            const int hl = f >> 2;
            const int r0 = (f & 3) * 4;
            AsT[(r0 + 0) * AT_STRIDE + hl] = v.x;
            AsT[(r0 + 1) * AT_STRIDE + hl] = v.y;
            AsT[(r0 + 2) * AT_STRIDE + hl] = v.z;
            AsT[(r0 + 3) * AT_STRIDE + hl] = v.w;
        }
    }
    {
        const int nl = tid & 63;
        const int rq = tid >> 6;        // 0..3
        #pragma unroll
        for (int j = 0; j < 4; ++j) {
            const int r = rq * 4 + j;
            Bsc[nl * 16 + r] = Bm[r * O + nn0 + nl] * LORA_SCALE;
        }
    }
    __syncthreads();

    const int wv_ = tid >> 6;
    const int lane = tid & 63;

    #pragma unroll
    for (int pass = 0; pass < 2; ++pass) {
        const int hl = pass * 256 + lane * 4;
        float4 areg[16];
        #pragma unroll
        for (int r = 0; r < 16; ++r)
            areg[r] = *(const float4*)(&AsT[r * AT_STRIDE + hl]);

        for (int i = 0; i < 16; ++i) {
            const int nl = wv_ * 16 + i;
            const float4 w4 = *(const float4*)(W + (size_t)(nn0 + nl) * Kdim + h0 + hl);
            const float4* b4 = (const float4*)(&Bsc[nl * 16]);
            float4 d = {0.f, 0.f, 0.f, 0.f};
            #pragma unroll
            for (int q = 0; q < 4; ++q) {
                const float4 b = b4[q];
                d.x += areg[q*4+0].x * b.x + areg[q*4+1].x * b.y + areg[q*4+2].x * b.z + areg[q*4+3].x * b.w;
                d.y += areg[q*4+0].y * b.x + areg[q*4+1].y * b.y + areg[q*4+2].y * b.z + areg[q*4+3].y * b.w;
                d.z += areg[q*4+0].z * b.x + areg[q*4+1].z * b.y + areg[q*4+2].z * b.z + areg[q*4+3].z * b.w;
                d.w += areg[q*4+0].w * b.x + areg[q*4+1].w * b.y + areg[q*4+2].w * b.z + areg[q*4+3].w * b.w;
            }
            ushort4 u;
            u.x = f2bf(w4.x + d.x); u.y = f2bf(w4.y + d.y);
            u.z = f2bf(w4.z + d.z); u.w = f2bf(w4.w + d.w);
            // k-preswizzled store: group (lane&7) -> (lane&7) ^ key(n)
            const int n = n0 + nl;
            const int key = (n >> 1) & 7;
            const int hs = (h0 + hl & ~31) | ((((h0 + hl) >> 2 & 7) ^ key) << 2);
            *(ushort4*)(Wf + (size_t)n * Kdim + hs) = u;
        }
    }
}

// ---------------------------------------------------------------------------
// GEMM: out[M, NTOT] = Xbf[M,K] . Wf[NTOT,K]^T + bias, scattered to q/k/v.
// LDS: A/B rings of 4 K-slices (slice = 2 halves x 128 rows x 32 k, 16 KB);
// staging DMA is linear (HBM already holds the 8-B-group swizzle).
// Frags: mfma_f32_32x32x16_bf16, read as 2x ds_read_b64 at phys groups
// (g)^key, (g+1)^key, key = (row>>1)&7 -> bank-conflict-free (b64 floor).
// Schedule ledger unchanged (8 phases / 4 slices, vmcnt(4) at ph3/ph7; peeled
// last iter: vmcnt(4) ph3 lands 126, vmcnt(0) ph5 lands 127).
// ---------------------------------------------------------------------------
__global__ __launch_bounds__(512, 2)
void gemm_qkv_kernel(const unsigned short* __restrict__ X,
                     const unsigned short* __restrict__ Wf,
                     const float* __restrict__ bq, const float* __restrict__ bk,
                     const float* __restrict__ bv,
                     float* __restrict__ out) {
    __shared__ __align__(16) unsigned short Abuf[4][8192];  // 64 KB
    __shared__ __align__(16) unsigned short Bbuf[4][8192];  // 64 KB

    const int tid  = threadIdx.x;
    const int lane = tid & 63;
    const int w    = tid >> 6;
    const int wr   = w >> 2;        // 0..1  (M half)
    const int wc   = w & 3;         // 0..3  (N quarter)

    int bid = blockIdx.x;
    bid = (bid & 7) * (NWG / 8) + (bid >> 3);   // XCD-aware, bijective (768%8==0)
    const int row0 = (bid / TILES_N) * BM;
    const int col0 = (bid % TILES_N) * BN;

    // frag read addressing: row = <win> + (lane&31); key = (row>>1)&7.
    // k-groups for (ks, kh=lane>>5): g_lo = ks*4 + kh*2, g_hi = g_lo+1;
    // phys byte offsets (g^key)*8.
    const int aRow0 = (wr * 128 + (lane & 31)) * 64;     // bytes
    const int bRow0 = (wc * 64  + (lane & 31)) * 64;     // bytes
    const int key   = (lane >> 1) & 7;
    int gofs[2][2];  // [ks][lo/hi] byte offsets
    #pragma unroll
    for (int ks = 0; ks < 2; ++ks) {
        const int g = ks * 4 + (lane >> 5) * 2;
        gofs[ks][0] = ((g    ) ^ key) << 3;
        gofs[ks][1] = ((g + 1) ^ key) << 3;
    }

    // staging source addressing (fully linear: HBM is pre-swizzled)
    const int srow = (w << 4) + (lane >> 2);                         // 0..127
    const int kofs = (lane & 3) * 8;                                 // elements
    const unsigned short* pA0 = X  + (size_t)(row0 + srow) * Kdim + kofs;
    const unsigned short* pA1 = pA0 + (size_t)128 * Kdim;
    const unsigned short* pB0 = Wf + (size_t)(col0 + srow) * Kdim + kofs;
    const unsigned short* pB1 = pB0 + (size_t)128 * Kdim;

    f32x16 acc[4][2];
    #pragma unroll
    for (int i = 0; i < 4; ++i)
        #pragma unroll
        for (int j = 0; j < 2; ++j)
            acc[i][j] = (f32x16)(0.f);

    short8 bfr[2][2];

#define LDFRAG(DST, BASE, ROWB, KS)                                              \
    { short4v lo_ = *(const short4v*)((BASE) + (ROWB) + gofs[KS][0]);            \
      short4v hi_ = *(const short4v*)((BASE) + (ROWB) + gofs[KS][1]);            \
      DST = __builtin_shufflevector(lo_, hi_, 0, 1, 2, 3, 4, 5, 6, 7); }

#define STAGE(MATA, SS)                                                          \
    { const int ss_ = (SS); const int st_ = (SS) & 3;                            \
      if (MATA) {                                                                \
        __builtin_amdgcn_global_load_lds((const GLOBAL_AS void*)(pA0 + ss_ * 32),\
            (LDS_AS void*)(&Abuf[st_][w * 512]),        16, 0, 0);               \
        __builtin_amdgcn_global_load_lds((const GLOBAL_AS void*)(pA1 + ss_ * 32),\
            (LDS_AS void*)(&Abuf[st_][4096 + w * 512]), 16, 0, 0);               \
      } else {                                                                   \
        __builtin_amdgcn_global_load_lds((const GLOBAL_AS void*)(pB0 + ss_ * 32),\
            (LDS_AS void*)(&Bbuf[st_][w * 512]),        16, 0, 0);               \
        __builtin_amdgcn_global_load_lds((const GLOBAL_AS void*)(pB1 + ss_ * 32),\
            (LDS_AS void*)(&Bbuf[st_][4096 + w * 512]), 16, 0, 0);               \
      } }

// WAITMODE: 0 = none, 1 = vmcnt(4), 2 = vmcnt(0)
#define DO_PHASE(G, MH, DOSTAGE, SMATA, SS, WAITMODE)                            \
    {                                                                            \
      const int slot_ = (G) & 3;                                                 \
      const char* abase_ = (const char*)Abuf + slot_ * 16384;                    \
      short8 af[2][2];                                                           \
      _Pragma("unroll")                                                          \
      for (int m = 0; m < 2; ++m)                                                \
        _Pragma("unroll")                                                        \
        for (int ks = 0; ks < 2; ++ks)                                           \
          LDFRAG(af[m][ks], abase_, aRow0 + (MH) * 4096 + m * 2048, ks);         \
      if ((MH) == 0) {                                                           \
        const char* bbase_ = (const char*)Bbuf + slot_ * 16384;                  \
        _Pragma("unroll")                                                        \
        for (int n = 0; n < 2; ++n)                                              \
          _Pragma("unroll")                                                      \
          for (int ks = 0; ks < 2; ++ks)                                         \
            LDFRAG(bfr[n][ks], bbase_, bRow0 + n * 2048, ks);                    \
      }                                                                          \
      if (DOSTAGE) STAGE(SMATA, SS);                                             \
      __builtin_amdgcn_s_barrier();                                              \
      asm volatile("s_waitcnt lgkmcnt(0)");                                      \
      __builtin_amdgcn_s_setprio(1);                                             \
      _Pragma("unroll")                                                          \
      for (int ks = 0; ks < 2; ++ks)                                             \
        _Pragma("unroll")                                                        \
        for (int m = 0; m < 2; ++m)                                              \
          _Pragma("unroll")                                                      \
          for (int n = 0; n < 2; ++n)                                            \
            acc[(MH) * 2 + m][n] = __builtin_amdgcn_mfma_f32_32x32x16_bf16(      \
                af[m][ks], bfr[n][ks], acc[(MH) * 2 + m][n], 0, 0, 0);           \
      __builtin_amdgcn_s_setprio(0);                                             \
      if ((WAITMODE) == 1) asm volatile("s_waitcnt vmcnt(4)" ::: "memory");      \
      if ((WAITMODE) == 2) asm volatile("s_waitcnt vmcnt(0)" ::: "memory");      \
      __builtin_amdgcn_s_barrier();                                              \
    }

    // ---- prologue: stage slices 0,1,2; land 0 and 1; keep 2 in flight ----
    STAGE(1, 0); STAGE(0, 0);
    STAGE(1, 1); STAGE(0, 1);
    STAGE(1, 2); STAGE(0, 2);
    asm volatile("s_waitcnt vmcnt(4)" ::: "memory");
    __builtin_amdgcn_s_barrier();

    for (int j = 0; j < NSLICE / 4 - 1; ++j) {
        const int g0 = j * 4;
        DO_PHASE(g0 + 0, 0, 1, 1, g0 + 3, 0);
        DO_PHASE(g0 + 0, 1, 1, 0, g0 + 3, 0);
        DO_PHASE(g0 + 1, 0, 1, 1, g0 + 4, 0);
        DO_PHASE(g0 + 1, 1, 1, 0, g0 + 4, 1);
        DO_PHASE(g0 + 2, 0, 1, 1, g0 + 5, 0);
        DO_PHASE(g0 + 2, 1, 1, 0, g0 + 5, 0);
        DO_PHASE(g0 + 3, 0, 1, 1, g0 + 6, 0);
        DO_PHASE(g0 + 3, 1, 1, 0, g0 + 6, 1);
    }
    // ---- peeled last iteration (g0 = 124): stage only slice 127 ----
    DO_PHASE(124, 0, 1, 1, 127, 0);
    DO_PHASE(124, 1, 1, 0, 127, 0);
    DO_PHASE(125, 0, 0, 0, 0,   0);
    DO_PHASE(125, 1, 0, 0, 0,   1);   // lands slice 126
    DO_PHASE(126, 0, 0, 0, 0,   0);
    DO_PHASE(126, 1, 0, 0, 0,   2);   // lands slice 127
    DO_PHASE(127, 0, 0, 0, 0,   0);
    DO_PHASE(127, 1, 0, 0, 0,   0);

#undef DO_PHASE
#undef STAGE
#undef LDFRAG

    // ---- epilogue: bias + scatter into q/k/v regions ----
    float* obase; int ldo; const float* bias; int cofs;
    if (col0 < NQ) {
        obase = out;                             ldo = NQ;  bias = bq; cofs = 0;
    } else if (col0 < NQ + NKV) {
        obase = out + (size_t)Mdim * NQ;         ldo = NKV; bias = bk; cofs = NQ;
    } else {
        obase = out + (size_t)Mdim * (NQ + NKV); ldo = NKV; bias = bv; cofs = NQ + NKV;
    }

    #pragma unroll
    for (int nf2 = 0; nf2 < 2; ++nf2) {
        const int col = col0 + wc * 64 + nf2 * 32 + (lane & 31) - cofs;
        const float b = bias[col];
        #pragma unroll
        for (int mf2 = 0; mf2 < 4; ++mf2) {
            #pragma unroll
            for (int r = 0; r < 16; ++r) {
                const int row = row0 + wr * 128 + mf2 * 32
                              + ((lane >> 5) << 2) + (r & 3) + ((r >> 2) << 3);
                obase[(size_t)row * ldo + col] = acc[mf2][nf2][r] + b;
            }
        }
    }
}

// ---------------------------------------------------------------------------
extern "C" void kernel_launch(void* const* d_in, const int* in_sizes, int n_in,
                              void* d_out, int out_size, void* d_ws, size_t ws_size,
                              hipStream_t stream) {
    const float* x  = (const float*)d_in[0];
    const float* Wq = (const float*)d_in[1];
    const float* Wk = (const float*)d_in[2];
    const float* Wv = (const float*)d_in[3];
    const float* bq = (const float*)d_in[4];
    const float* bk = (const float*)d_in[5];
    const float* bv = (const float*)d_in[6];
    const float* Aq = (const float*)d_in[7];
    const float* Bq = (const float*)d_in[8];
    const float* Ak = (const float*)d_in[9];
    const float* Bk = (const float*)d_in[10];
    const float* Av = (const float*)d_in[11];
    const float* Bv = (const float*)d_in[12];
    float* out = (float*)d_out;

    unsigned short* Xbf = (unsigned short*)d_ws;                   // 64 MB
    unsigned short* Wf  = Xbf + (size_t)Mdim * Kdim;               // 48 MB

    prep_kernel<<<WEFF_BLOCKS + CVT_BLOCKS, 256, 0, stream>>>(
        (const float4*)x, Xbf, Wq, Wk, Wv, Aq, Bq, Ak, Bk, Av, Bv, Wf);

    gemm_qkv_kernel<<<NWG, 512, 0, stream>>>(Xbf, Wf, bq, bk, bv, out);
}

// Round 7
// 472.861 us; speedup vs baseline: 1.0955x; 1.0955x over previous
//
#include <hip/hip_runtime.h>

// ---------------------------------------------------------------------------
// LoRA QKV fused projection on MI355X (gfx950)
// Weff-folding (LoRA into weights) + ONE bf16 MFMA GEMM (16x16x32 frags,
// R4's verified conflict-free 16-B-chunk swizzle).
// R7: software-pipelined phases — each phase pre-reads the NEXT phase's
//     frags into ping-pong register sets (compile-time indices), MFMA runs
//     on current regs, ONE barrier per phase (begin-barrier dropped; WAR
//     safety re-derived), vmcnt(6) at even-phase ends publishes slice s+1
//     exactly one phase before its pre-read. Barriers/iter 16 -> 8; LDS-read
//     pipe now overlaps MFMA pipe instead of serializing with it.
// ---------------------------------------------------------------------------

#define GLOBAL_AS __attribute__((address_space(1)))
#define LDS_AS    __attribute__((address_space(3)))

typedef __attribute__((ext_vector_type(8))) short  short8;   // 8 bf16 (MFMA A/B frag)
typedef __attribute__((ext_vector_type(4))) float  floatx4;  // MFMA C/D frag

constexpr int Mdim = 8192;   // B*S
constexpr int Kdim = 4096;   // H
constexpr int NQ   = 4096;
constexpr int NKV  = 1024;
constexpr int NTOT = NQ + 2 * NKV;  // 6144
constexpr float LORA_SCALE = 2.0f;

constexpr int BM = 256, BN = 256;
constexpr int TILES_M = Mdim / BM;      // 32
constexpr int TILES_N = NTOT / BN;      // 24
constexpr int NWG = TILES_M * TILES_N;  // 768 (%8==0 -> bijective XCD swizzle)
constexpr int NSLICE = Kdim / 32;       // 128 K-slices of 32

constexpr int WEFF_BLOCKS = (NTOT / 64) * (Kdim / 512);  // 768
constexpr int CVT_BLOCKS  = 2048;
constexpr int AT_STRIDE   = 516;

__device__ __forceinline__ unsigned short f2bf(float f) {
    union { float f; unsigned int u; } a; a.f = f;
    unsigned int r = a.u + 0x7FFFu + ((a.u >> 16) & 1u);
    return (unsigned short)(r >> 16);
}

// ---------------------------------------------------------------------------
// Fused prep (R4 version — linear writes; GEMM staging applies the swizzle
// via its per-lane source addressing):
//   blocks [0, WEFF_BLOCKS): Weff[n,h] = W[n,h] + 2*sum_r A[h,r]B[r,n] -> bf16
//   blocks [WEFF_BLOCKS, +CVT_BLOCKS): X fp32 -> bf16.
// ---------------------------------------------------------------------------
__global__ __launch_bounds__(256)
void prep_kernel(const float4* __restrict__ x4, unsigned short* __restrict__ Xbf,
                 const float* __restrict__ Wq, const float* __restrict__ Wk,
                 const float* __restrict__ Wv,
                 const float* __restrict__ Aq, const float* __restrict__ Bq,
                 const float* __restrict__ Ak, const float* __restrict__ Bk,
                 const float* __restrict__ Av, const float* __restrict__ Bv,
                 unsigned short* __restrict__ Wf) {
    __shared__ float AsT[16 * AT_STRIDE];   // ~33 KB: A^T chunk, [r][h_local]
    __shared__ float Bsc[64 * 16];          // 4 KB: 2*B[r, n0+..] as [n][r]

    const int tid = threadIdx.x;

    if (blockIdx.x >= WEFF_BLOCKS) {
        int i = (blockIdx.x - WEFF_BLOCKS) * 256 + tid;
        const int stride = CVT_BLOCKS * 256;
        const int n4 = Mdim * Kdim / 4;
        ushort4* out = (ushort4*)Xbf;
        for (; i < n4; i += stride) {
            float4 v = x4[i];
            ushort4 u;
            u.x = f2bf(v.x); u.y = f2bf(v.y); u.z = f2bf(v.z); u.w = f2bf(v.w);
            out[i] = u;
        }
        return;
    }

    const int n0 = (blockIdx.x >> 3) * 64;      // 64-row group (never straddles seg)
    const int h0 = (blockIdx.x & 7) * 512;

    const float* W; const float* A; const float* Bm; int O; int nn0;
    if (n0 < NQ)            { W = Wq; A = Aq; Bm = Bq; O = NQ;  nn0 = n0; }
    else if (n0 < NQ + NKV) { W = Wk; A = Ak; Bm = Bk; O = NKV; nn0 = n0 - NQ; }
    else                    { W = Wv; A = Av; Bm = Bv; O = NKV; nn0 = n0 - NQ - NKV; }

    {
        const float4* Af4 = (const float4*)(A) + h0 * 4;
        #pragma unroll
        for (int i = 0; i < 8; ++i) {
            const int f = i * 256 + tid;
            const float4 v = Af4[f];
            const int hl = f >> 2;
            const int r0 = (f & 3) * 4;
            AsT[(r0 + 0) * AT_STRIDE + hl] = v.x;
            AsT[(r0 + 1) * AT_STRIDE + hl] = v.y;
            AsT[(r0 + 2) * AT_STRIDE + hl] = v.z;
            AsT[(r0 + 3) * AT_STRIDE + hl] = v.w;
        }
    }
    {
        const int nl = tid & 63;
        const int rq = tid >> 6;        // 0..3
        #pragma unroll
        for (int j = 0; j < 4; ++j) {
            const int r = rq * 4 + j;
            Bsc[nl * 16 + r] = Bm[r * O + nn0 + nl] * LORA_SCALE;
        }
    }
    __syncthreads();

    const int wv_ = tid >> 6;
    const int lane = tid & 63;

    #pragma unroll
    for (int pass = 0; pass < 2; ++pass) {
        const int hl = pass * 256 + lane * 4;
        float4 areg[16];
        #pragma unroll
        for (int r = 0; r < 16; ++r)
            areg[r] = *(const float4*)(&AsT[r * AT_STRIDE + hl]);

        for (int i = 0; i < 16; ++i) {
            const int nl = wv_ * 16 + i;
            const float4 w4 = *(const float4*)(W + (size_t)(nn0 + nl) * Kdim + h0 + hl);
            const float4* b4 = (const float4*)(&Bsc[nl * 16]);
            float4 d = {0.f, 0.f, 0.f, 0.f};
            #pragma unroll
            for (int q = 0; q < 4; ++q) {
                const float4 b = b4[q];
                d.x += areg[q*4+0].x * b.x + areg[q*4+1].x * b.y + areg[q*4+2].x * b.z + areg[q*4+3].x * b.w;
                d.y += areg[q*4+0].y * b.x + areg[q*4+1].y * b.y + areg[q*4+2].y * b.z + areg[q*4+3].y * b.w;
                d.z += areg[q*4+0].z * b.x + areg[q*4+1].z * b.y + areg[q*4+2].z * b.z + areg[q*4+3].z * b.w;
                d.w += areg[q*4+0].w * b.x + areg[q*4+1].w * b.y + areg[q*4+2].w * b.z + areg[q*4+3].w * b.w;
            }
            ushort4 u;
            u.x = f2bf(w4.x + d.x); u.y = f2bf(w4.y + d.y);
            u.z = f2bf(w4.z + d.z); u.w = f2bf(w4.w + d.w);
            *(ushort4*)(Wf + (size_t)(n0 + nl) * Kdim + h0 + hl) = u;
        }
    }
}

// ---------------------------------------------------------------------------
// GEMM: out[M, NTOT] = Xbf[M,K] . Wf[NTOT,K]^T + bias, scattered to q/k/v.
//
// LDS: A/B rings of 4 K-slices (slice = 2 halves x 128 rows x 32 k, 16 KB).
// Slices g..g+3 of iter j (g=4j) occupy slots 0..3 (compile-time).
// Phase q=(s,MH): pre-read frags for q+1 into the OTHER ping-pong reg set,
// stage per schedule, MFMA on current set, counted vmcnt at even phases,
// ONE s_barrier at phase end.
//   reg sets: afr[q&1] = A-frags of phase q; bfr[s&1] = B-frags of slice s.
// Retirement ledger (steady state, queue in 2-load entries):
//   start of iter: [A(g+1),B(g+1),A(g+2),B(g+2)]
//   p0 +A(g+3) ->10, vmcnt(6) retires g+1 (pre-read at p1)
//   p1 +B(g+3) -> 8
//   p2 +A(g+4) ->10, vmcnt(6) retires g+2 (pre-read at p3)
//   p3 +B(g+4) -> 8
//   p4 +A(g+5) ->10, vmcnt(6) retires g+3 (pre-read at p5)
//   p5 +B(g+5) -> 8
//   p6 +A(g+6) ->10, vmcnt(6) retires g+4 (pre-read at p7)
//   p7 +B(g+6) -> 8   (never drains to 0)
// Peeled final iter (g=124): stages only slice 127 at p0/p1; waits
// vmcnt(6)@p0 (125), vmcnt(4)@p2 (126), vmcnt(0)@p4 (127); no tail garbage.
// ---------------------------------------------------------------------------
__global__ __launch_bounds__(512, 2)
void gemm_qkv_kernel(const unsigned short* __restrict__ X,
                     const unsigned short* __restrict__ Wf,
                     const float* __restrict__ bq, const float* __restrict__ bk,
                     const float* __restrict__ bv,
                     float* __restrict__ out) {
    __shared__ __align__(16) unsigned short Abuf[4][8192];  // 64 KB
    __shared__ __align__(16) unsigned short Bbuf[4][8192];  // 64 KB

    const int tid  = threadIdx.x;
    const int lane = tid & 63;
    const int w    = tid >> 6;
    const int wr   = w >> 2;        // 0..1  (M half)
    const int wc   = w & 3;         // 0..3  (N quarter)

    int bid = blockIdx.x;
    bid = (bid & 7) * (NWG / 8) + (bid >> 3);   // XCD-aware, bijective (768%8==0)
    const int row0 = (bid / TILES_N) * BM;
    const int col0 = (bid % TILES_N) * BN;

    // ds_read addressing (16-B chunk swizzle, verified conflict-free in R4):
    // lane reads row (lane&15), k-chunk kh=lane>>4 from phys chunk kh^((row>>1)&3)
    const int swz    = (((lane >> 4) ^ ((lane >> 1) & 3)) << 4);    // bytes
    const int aByte0 = (wr * 128 + (lane & 15)) * 64 + swz;
    const int bByte0 = (wc * 64  + (lane & 15)) * 64 + swz;

    // staging source addressing (pre-permuted k so linear LDS dest ends swizzled)
    const int srow = (w << 4) + (lane >> 2);                         // 0..127
    const int kswz = (((lane & 3) ^ ((lane >> 3) & 3)) << 3);        // elements
    const unsigned short* pA0 = X  + (size_t)(row0 + srow) * Kdim + kswz;
    const unsigned short* pA1 = pA0 + (size_t)128 * Kdim;
    const unsigned short* pB0 = Wf + (size_t)(col0 + srow) * Kdim + kswz;
    const unsigned short* pB1 = pB0 + (size_t)128 * Kdim;

    floatx4 acc[8][4];
    #pragma unroll
    for (int i = 0; i < 8; ++i)
        #pragma unroll
        for (int j = 0; j < 4; ++j)
            acc[i][j] = (floatx4){0.f, 0.f, 0.f, 0.f};

    short8 afr[2][4];   // A-frag ping-pong by phase parity
    short8 bfr[2][4];   // B-frag ping-pong by slice parity

#define STAGE(MATA, SS, SLOT)                                                    \
    { const int ss_ = (SS);                                                      \
      if (MATA) {                                                                \
        __builtin_amdgcn_global_load_lds((const GLOBAL_AS void*)(pA0 + ss_ * 32),\
            (LDS_AS void*)(&Abuf[SLOT][w * 512]),        16, 0, 0);              \
        __builtin_amdgcn_global_load_lds((const GLOBAL_AS void*)(pA1 + ss_ * 32),\
            (LDS_AS void*)(&Abuf[SLOT][4096 + w * 512]), 16, 0, 0);              \
      } else {                                                                   \
        __builtin_amdgcn_global_load_lds((const GLOBAL_AS void*)(pB0 + ss_ * 32),\
            (LDS_AS void*)(&Bbuf[SLOT][w * 512]),        16, 0, 0);              \
        __builtin_amdgcn_global_load_lds((const GLOBAL_AS void*)(pB1 + ss_ * 32),\
            (LDS_AS void*)(&Bbuf[SLOT][4096 + w * 512]), 16, 0, 0);              \
      } }

#define READA(P, SLOT, MH)                                                       \
    { const char* ab_ = (const char*)Abuf + (SLOT) * 16384;                      \
      _Pragma("unroll")                                                          \
      for (int mf = 0; mf < 4; ++mf)                                             \
        afr[P][mf] = *(const short8*)(ab_ + aByte0 + ((MH) * 4 + mf) * 1024); }

#define READB(P, SLOT)                                                           \
    { const char* bb_ = (const char*)Bbuf + (SLOT) * 16384;                      \
      _Pragma("unroll")                                                          \
      for (int nf = 0; nf < 4; ++nf)                                             \
        bfr[P][nf] = *(const short8*)(bb_ + bByte0 + nf * 1024); }

#define MFMA16(PA, PB, MH)                                                       \
    { __builtin_amdgcn_s_setprio(1);                                             \
      _Pragma("unroll")                                                          \
      for (int mf = 0; mf < 4; ++mf)                                             \
        _Pragma("unroll")                                                        \
        for (int nf = 0; nf < 4; ++nf)                                           \
          acc[(MH) * 4 + mf][nf] = __builtin_amdgcn_mfma_f32_16x16x32_bf16(      \
              afr[PA][mf], bfr[PB][nf], acc[(MH) * 4 + mf][nf], 0, 0, 0);        \
      __builtin_amdgcn_s_setprio(0); }

// PRA: pre-read A for next phase (0 = skip); PRB: pre-read B (0 = skip)
// WM: 0 none, 1 vmcnt(6), 2 vmcnt(4), 3 vmcnt(0); BAR: s_barrier at end
#define PHASE(PAC, PBC, MH, PRA, NAP, NSLOT, NMH, PRB, NBP, DOST, SM, SS, SSLOT, WM, BAR) \
    { if (PRA) READA(NAP, NSLOT, NMH);                                           \
      if (PRB) READB(NBP, NSLOT);                                                \
      if (DOST) STAGE(SM, SS, SSLOT);                                            \
      MFMA16(PAC, PBC, MH);                                                      \
      if ((WM) == 1) asm volatile("s_waitcnt vmcnt(6)" ::: "memory");            \
      if ((WM) == 2) asm volatile("s_waitcnt vmcnt(4)" ::: "memory");            \
      if ((WM) == 3) asm volatile("s_waitcnt vmcnt(0)" ::: "memory");            \
      if (BAR) __builtin_amdgcn_s_barrier(); }

    // ---- prologue: stage slices 0,1,2; land slice 0; pre-read (0,MH0) ----
    STAGE(1, 0, 0); STAGE(0, 0, 0);
    STAGE(1, 1, 1); STAGE(0, 1, 1);
    STAGE(1, 2, 2); STAGE(0, 2, 2);
    asm volatile("s_waitcnt vmcnt(8)" ::: "memory");
    __builtin_amdgcn_s_barrier();
    READA(0, 0, 0);
    READB(0, 0);

    for (int j = 0; j < NSLICE / 4 - 1; ++j) {
        const int g = j * 4;
        //    PAC PBC MH  PRA NAP NSLOT NMH PRB NBP  DOST SM  SS     SSLOT WM BAR
        PHASE(0,  0,  0,  1,  1,  0,    1,  0,  0,   1,   1,  g + 3, 3,    1, 1);
        PHASE(1,  0,  1,  1,  0,  1,    0,  1,  1,   1,   0,  g + 3, 3,    0, 1);
        PHASE(0,  1,  0,  1,  1,  1,    1,  0,  0,   1,   1,  g + 4, 0,    1, 1);
        PHASE(1,  1,  1,  1,  0,  2,    0,  1,  0,   1,   0,  g + 4, 0,    0, 1);
        PHASE(0,  0,  0,  1,  1,  2,    1,  0,  0,   1,   1,  g + 5, 1,    1, 1);
        PHASE(1,  0,  1,  1,  0,  3,    0,  1,  1,   1,   0,  g + 5, 1,    0, 1);
        PHASE(0,  1,  0,  1,  1,  3,    1,  0,  0,   1,   1,  g + 6, 2,    1, 1);
        PHASE(1,  1,  1,  1,  0,  0,    0,  1,  0,   1,   0,  g + 6, 2,    0, 1);
    }
    // ---- peeled final iteration (g = 124, slices 124..127 in slots 0..3) ----
    PHASE(0, 0, 0,  1, 1, 0, 1,  0, 0,  1, 1, 127, 3,  1, 1);
    PHASE(1, 0, 1,  1, 0, 1, 0,  1, 1,  1, 0, 127, 3,  0, 1);
    PHASE(0, 1, 0,  1, 1, 1, 1,  0, 0,  0, 0, 0,   0,  2, 1);
    PHASE(1, 1, 1,  1, 0, 2, 0,  1, 0,  0, 0, 0,   0,  0, 1);
    PHASE(0, 0, 0,  1, 1, 2, 1,  0, 0,  0, 0, 0,   0,  3, 1);
    PHASE(1, 0, 1,  1, 0, 3, 0,  1, 1,  0, 0, 0,   0,  0, 1);
    PHASE(0, 1, 0,  1, 1, 3, 1,  0, 0,  0, 0, 0,   0,  0, 1);
    PHASE(1, 1, 1,  0, 0, 0, 0,  0, 0,  0, 0, 0,   0,  0, 0);

#undef PHASE
#undef MFMA16
#undef READB
#undef READA
#undef STAGE

    // ---- epilogue: bias + scatter into q/k/v regions ----
    float* obase; int ldo; const float* bias; int cofs;
    if (col0 < NQ) {
        obase = out;                             ldo = NQ;  bias = bq; cofs = 0;
    } else if (col0 < NQ + NKV) {
        obase = out + (size_t)Mdim * NQ;         ldo = NKV; bias = bk; cofs = NQ;
    } else {
        obase = out + (size_t)Mdim * (NQ + NKV); ldo = NKV; bias = bv; cofs = NQ + NKV;
    }

    #pragma unroll
    for (int nf = 0; nf < 4; ++nf) {
        const int col = col0 + wc * 64 + nf * 16 + (lane & 15) - cofs;
        const float b = bias[col];
        #pragma unroll
        for (int mf = 0; mf < 8; ++mf) {
            #pragma unroll
            for (int r = 0; r < 4; ++r) {
                const int row = row0 + wr * 128 + mf * 16 + (lane >> 4) * 4 + r;
                obase[(size_t)row * ldo + col] = acc[mf][nf][r] + b;
            }
        }
    }
}

// ---------------------------------------------------------------------------
extern "C" void kernel_launch(void* const* d_in, const int* in_sizes, int n_in,
                              void* d_out, int out_size, void* d_ws, size_t ws_size,
                              hipStream_t stream) {
    const float* x  = (const float*)d_in[0];
    const float* Wq = (const float*)d_in[1];
    const float* Wk = (const float*)d_in[2];
    const float* Wv = (const float*)d_in[3];
    const float* bq = (const float*)d_in[4];
    const float* bk = (const float*)d_in[5];
    const float* bv = (const float*)d_in[6];
    const float* Aq = (const float*)d_in[7];
    const float* Bq = (const float*)d_in[8];
    const float* Ak = (const float*)d_in[9];
    const float* Bk = (const float*)d_in[10];
    const float* Av = (const float*)d_in[11];
    const float* Bv = (const float*)d_in[12];
    float* out = (float*)d_out;

    unsigned short* Xbf = (unsigned short*)d_ws;                   // 64 MB
    unsigned short* Wf  = Xbf + (size_t)Mdim * Kdim;               // 48 MB

    prep_kernel<<<WEFF_BLOCKS + CVT_BLOCKS, 256, 0, stream>>>(
        (const float4*)x, Xbf, Wq, Wk, Wv, Aq, Bq, Ak, Bk, Av, Bv, Wf);

    gemm_qkv_kernel<<<NWG, 512, 0, stream>>>(Xbf, Wf, bq, bk, bv, out);
}